// Round 1
// baseline (5051.054 us; speedup 1.0000x reference)
//
#include <hip/hip_runtime.h>

#define Tn 8
#define Nn 10000
#define FIN 128
#define Hh 64
#define En 160000

typedef _Float16 h8 __attribute__((ext_vector_type(8)));
typedef float f4v __attribute__((ext_vector_type(4)));

__device__ __forceinline__ float sigm(float x) {
    float e = __builtin_amdgcn_exp2f(-1.4426950408889634f * x);
    return __builtin_amdgcn_rcpf(1.0f + e);
}
__device__ __forceinline__ float tanh_(float x) {
    float e = __builtin_amdgcn_exp2f(2.8853900817779268f * x);
    return 1.0f - 2.0f * __builtin_amdgcn_rcpf(1.0f + e);
}

// edge_index may arrive as int32 or int64; detect by checking high words.
__global__ void k_detect(const unsigned* ei, int* flag) {
    unsigned a = 0;
    for (int i = threadIdx.x; i < 4096; i += 64) a |= ei[2 * i + 1];
    unsigned long long b = __ballot(a != 0);
    if (threadIdx.x == 0) flag[0] = (b != 0ull) ? 1 : 0;  // 1 => int32
}

__device__ __forceinline__ int eget(const void* ei, int is32, size_t pos) {
    return is32 ? ((const int*)ei)[pos] : (int)((const long long*)ei)[pos];
}

__global__ void k_deg(const void* ei, const int* flag, float* deg) {
    int tid = blockIdx.x * 256 + threadIdx.x;  // exactly Tn*En
    int is32 = *flag;
    int t = tid / En, e = tid - t * En;
    int dst = eget(ei, is32, (size_t)t * 2 * En + En + e);
    atomicAdd(&deg[t * Nn + dst], 1.0f);
}

__global__ void k_dinv(float* deg) {
    int i = blockIdx.x * 256 + threadIdx.x;
    if (i < Tn * Nn) deg[i] = rsqrtf(deg[i] + 1.0f);  // +1 self-loop
}

// h = x @ W_gcn   [Tn*Nn,128] @ [128,64]
__global__ void k_gcn_mm(const float* __restrict__ x, const float* __restrict__ Wg,
                         float* __restrict__ h) {
    __shared__ float wl[FIN * Hh];
    __shared__ float xs[4][FIN];
    int tid = threadIdx.x;
    const float4* Wg4 = (const float4*)Wg;
    float4* wl4 = (float4*)wl;
    for (int i = tid; i < FIN * Hh / 4; i += 256) wl4[i] = Wg4[i];
    int r0 = blockIdx.x * 4;
    const float4* x4 = (const float4*)x + (size_t)r0 * (FIN / 4);
    if (tid < 128) ((float4*)xs)[tid] = x4[tid];
    __syncthreads();
    int c = tid & 63, j = tid >> 6;
    float acc = 0.f;
#pragma unroll 8
    for (int k = 0; k < FIN; k++) acc += xs[j][k] * wl[k * Hh + c];
    h[(size_t)(r0 + j) * Hh + c] = acc;
}

__global__ void k_self(const float* __restrict__ h, const float* __restrict__ dinv,
                       float* __restrict__ gout) {
    int i = blockIdx.x * 256 + threadIdx.x;  // exactly Tn*Nn*Hh
    int r = i >> 6;
    float d = dinv[r];
    gout[i] = h[i] * d * d;
}

__global__ void k_scatter(const void* ei, const int* flag, const float* __restrict__ h,
                          const float* __restrict__ dinv, float* gout) {
    int u = blockIdx.x * 256 + threadIdx.x;  // exactly Tn*En*16
    int f4i = u & 15;
    int te = u >> 4;
    int t = te / En, e = te - t * En;
    int is32 = *flag;
    int src = eget(ei, is32, (size_t)t * 2 * En + e);
    int dst = eget(ei, is32, (size_t)t * 2 * En + En + e);
    float nrm = dinv[t * Nn + src] * dinv[t * Nn + dst];
    float4 v = *((const float4*)(h + (size_t)(t * Nn + src) * Hh) + f4i);
    float* gp = gout + (size_t)(t * Nn + dst) * Hh + f4i * 4;
    atomicAdd(gp + 0, v.x * nrm);
    atomicAdd(gp + 1, v.y * nrm);
    atomicAdd(gp + 2, v.z * nrm);
    atomicAdd(gp + 3, v.w * nrm);
}

// xw = relu(gout + b_gcn) @ W_ih^T + b_ih + b_hh  -> f16 [Tn*Nn][256]
__global__ void k_xw(const float* __restrict__ gout, const float* __restrict__ bg,
                     const float* __restrict__ Wih, const float* __restrict__ bih,
                     const float* __restrict__ bhh, _Float16* __restrict__ xw) {
    __shared__ float xs[8 * Hh];
    int tid = threadIdx.x;
    int r0 = blockIdx.x * 8;
    if (tid < 128) {
        float4 v = ((const float4*)(gout + (size_t)r0 * Hh))[tid];
        float4 b = ((const float4*)bg)[tid & 15];
        v.x = fmaxf(v.x + b.x, 0.f);
        v.y = fmaxf(v.y + b.y, 0.f);
        v.z = fmaxf(v.z + b.z, 0.f);
        v.w = fmaxf(v.w + b.w, 0.f);
        ((float4*)xs)[tid] = v;
    }
    __syncthreads();
    int r = tid;
    const float4* w4 = (const float4*)(Wih + (size_t)r * Hh);
    float acc[8];
#pragma unroll
    for (int j = 0; j < 8; j++) acc[j] = 0.f;
#pragma unroll
    for (int kk = 0; kk < 16; kk++) {
        float4 w = w4[kk];
#pragma unroll
        for (int j = 0; j < 8; j++) {
            float4 xv = ((const float4*)xs)[j * 16 + kk];
            acc[j] += w.x * xv.x + w.y * xv.y + w.z * xv.z + w.w * xv.w;
        }
    }
    float bias = bih[r] + bhh[r];
#pragma unroll
    for (int j = 0; j < 8; j++)
        xw[(size_t)(r0 + j) * 256 + r] = (_Float16)(acc[j] + bias);
}

// One chain (t) per block. 4 waves; wave w owns gate columns 16w..16w+15 of
// all 4 quadrants, so i,f,g,o for one h-index live in one lane. W_hh^T stays
// in B-frag registers; h crosses steps via 128B LDS double buffer, 1 barrier/step.
__global__ void __launch_bounds__(256) k_lstm(const _Float16* __restrict__ xw,
                                              const float* __restrict__ Whh,
                                              float* __restrict__ out) {
    __shared__ __align__(16) _Float16 hb[2][64];
    int t = blockIdx.x;
    int tid = threadIdx.x;
    int w = tid >> 6;
    int lane = tid & 63;
    int l = lane & 15;
    int kg = lane >> 4;

    h8 bf[4][2];
#pragma unroll
    for (int q = 0; q < 4; q++) {
        int row = q * 64 + w * 16 + l;
#pragma unroll
        for (int kap = 0; kap < 2; kap++) {
            const float* src = Whh + (size_t)row * 64 + kg * 8 + kap * 32;
            h8 tmp;
#pragma unroll
            for (int j = 0; j < 8; j++) tmp[j] = (_Float16)src[j];
            bf[q][kap] = tmp;
        }
    }
    if (tid < 128) hb[tid >> 6][tid & 63] = (_Float16)0.f;
    __syncthreads();

    const _Float16* xwb = xw + (size_t)t * Nn * 256;
    float* ob = out + (size_t)t * Nn * 64;
    float xwc[4], xwn[4];
#pragma unroll
    for (int q = 0; q < 4; q++) xwc[q] = (float)xwb[q * 64 + w * 16 + l];
    float c = 0.f;

    for (int n = 0; n < Nn; n++) {
        f4v acc0 = {xwc[0], 0.f, 0.f, 0.f};
        f4v acc1 = {xwc[1], 0.f, 0.f, 0.f};
        f4v acc2 = {xwc[2], 0.f, 0.f, 0.f};
        f4v acc3 = {xwc[3], 0.f, 0.f, 0.f};
        int nn = (n + 1 < Nn) ? n + 1 : n;
#pragma unroll
        for (int q = 0; q < 4; q++)
            xwn[q] = (float)xwb[(size_t)nn * 256 + q * 64 + w * 16 + l];
        h8 a0 = *(const h8*)&hb[n & 1][kg * 8];
        h8 a1 = *(const h8*)&hb[n & 1][32 + kg * 8];
        acc0 = __builtin_amdgcn_mfma_f32_16x16x32_f16(a0, bf[0][0], acc0, 0, 0, 0);
        acc0 = __builtin_amdgcn_mfma_f32_16x16x32_f16(a1, bf[0][1], acc0, 0, 0, 0);
        acc1 = __builtin_amdgcn_mfma_f32_16x16x32_f16(a0, bf[1][0], acc1, 0, 0, 0);
        acc1 = __builtin_amdgcn_mfma_f32_16x16x32_f16(a1, bf[1][1], acc1, 0, 0, 0);
        acc2 = __builtin_amdgcn_mfma_f32_16x16x32_f16(a0, bf[2][0], acc2, 0, 0, 0);
        acc2 = __builtin_amdgcn_mfma_f32_16x16x32_f16(a1, bf[2][1], acc2, 0, 0, 0);
        acc3 = __builtin_amdgcn_mfma_f32_16x16x32_f16(a0, bf[3][0], acc3, 0, 0, 0);
        acc3 = __builtin_amdgcn_mfma_f32_16x16x32_f16(a1, bf[3][1], acc3, 0, 0, 0);

        float iv = sigm(acc0[0]);
        float fv = sigm(acc1[0]);
        float gv = tanh_(acc2[0]);
        float ov = sigm(acc3[0]);
        c = fv * c + iv * gv;
        float hv = ov * tanh_(c);
        if (lane < 16) {
            ob[(size_t)n * 64 + w * 16 + l] = hv;
            hb[(n + 1) & 1][w * 16 + l] = (_Float16)hv;
        }
        __syncthreads();
#pragma unroll
        for (int q = 0; q < 4; q++) xwc[q] = xwn[q];
    }
}

extern "C" void kernel_launch(void* const* d_in, const int* in_sizes, int n_in,
                              void* d_out, int out_size, void* d_ws, size_t ws_size,
                              hipStream_t stream) {
    const float* x = (const float*)d_in[0];
    const void* ei = d_in[1];
    const float* Wg = (const float*)d_in[2];
    const float* bg = (const float*)d_in[3];
    const float* Wih = (const float*)d_in[4];
    const float* Whh = (const float*)d_in[5];
    const float* bih = (const float*)d_in[6];
    const float* bhh = (const float*)d_in[7];
    float* out = (float*)d_out;

    char* ws = (char*)d_ws;
    _Float16* xw = (_Float16*)ws;              // 40,960,000 B
    float* gout = (float*)(ws + 40960000);     // 20,480,000 B
    float* deg = (float*)(ws + 61440000);      //    320,000 B (deg -> dinv in place)
    float* h = (float*)(ws + 61760000);        // 20,480,000 B
    int* flag = (int*)(ws + 82240000);         // 16 B  (total ~82.3 MB)

    hipMemsetAsync(deg, 0, Tn * Nn * sizeof(float), stream);
    k_detect<<<1, 64, 0, stream>>>((const unsigned*)ei, flag);
    k_deg<<<Tn * En / 256, 256, 0, stream>>>(ei, flag, deg);
    k_dinv<<<(Tn * Nn + 255) / 256, 256, 0, stream>>>(deg);
    k_gcn_mm<<<Tn * Nn / 4, 256, 0, stream>>>(x, Wg, h);
    k_self<<<Tn * Nn * Hh / 256, 256, 0, stream>>>(h, deg, gout);
    k_scatter<<<Tn * En * 16 / 256, 256, 0, stream>>>(ei, flag, h, deg, gout);
    k_xw<<<Tn * Nn / 8, 256, 0, stream>>>(gout, bg, Wih, bih, bhh, xw);
    k_lstm<<<Tn, 256, 0, stream>>>(xw, Whh, out);
}

// Round 2
// 5029.793 us; speedup vs baseline: 1.0042x; 1.0042x over previous
//
#include <hip/hip_runtime.h>

#define Tn 8
#define Nn 10000
#define FIN 128
#define Hh 64
#define En 160000
#define NODES (Tn * Nn)

typedef _Float16 h8 __attribute__((ext_vector_type(8)));
typedef _Float16 h4 __attribute__((ext_vector_type(4)));
typedef float f4v __attribute__((ext_vector_type(4)));

__device__ __forceinline__ float sigm(float x) {
    float e = __builtin_amdgcn_exp2f(-1.4426950408889634f * x);
    return __builtin_amdgcn_rcpf(1.0f + e);
}
__device__ __forceinline__ float tanh_(float x) {
    float e = __builtin_amdgcn_exp2f(2.8853900817779268f * x);
    return 1.0f - 2.0f * __builtin_amdgcn_rcpf(1.0f + e);
}

// edge_index may arrive as int32 or int64; detect by checking high words.
__global__ void k_detect(const unsigned* ei, int* flag) {
    unsigned a = 0;
    for (int i = threadIdx.x; i < 4096; i += 64) a |= ei[2 * i + 1];
    unsigned long long b = __ballot(a != 0);
    if (threadIdx.x == 0) flag[0] = (b != 0ull) ? 1 : 0;  // 1 => int32
}

__device__ __forceinline__ int eget(const void* ei, int is32, size_t pos) {
    return is32 ? ((const int*)ei)[pos] : (int)((const long long*)ei)[pos];
}

__global__ void k_cnt(const void* ei, const int* flag, int* cnt) {
    int tid = blockIdx.x * 256 + threadIdx.x;  // exactly Tn*En
    int is32 = *flag;
    int t = tid / En, e = tid - t * En;
    int dst = eget(ei, is32, (size_t)t * 2 * En + En + e);
    atomicAdd(&cnt[t * Nn + dst], 1);
}

__global__ void k_dinv(const int* cnt, float* dinv) {
    int i = blockIdx.x * 256 + threadIdx.x;
    if (i < NODES) dinv[i] = rsqrtf((float)cnt[i] + 1.0f);  // +1 self-loop
}

// --- exclusive prefix sum over cnt[NODES]: A) block sums, B) scan sums, C) combine
__global__ void k_scanA(const int* cnt, int* bsum) {
    __shared__ int sh[256];
    int i = blockIdx.x * 256 + threadIdx.x;
    sh[threadIdx.x] = (i < NODES) ? cnt[i] : 0;
    __syncthreads();
    for (int s = 128; s > 0; s >>= 1) {
        if (threadIdx.x < s) sh[threadIdx.x] += sh[threadIdx.x + s];
        __syncthreads();
    }
    if (threadIdx.x == 0) bsum[blockIdx.x] = sh[0];
}

__global__ void k_scanB(int* bsum, int nb) {
    __shared__ int sh[512];
    int v = (threadIdx.x < nb) ? bsum[threadIdx.x] : 0;
    sh[threadIdx.x] = v;
    __syncthreads();
    for (int s = 1; s < 512; s <<= 1) {
        int a = ((int)threadIdx.x >= s) ? sh[threadIdx.x - s] : 0;
        __syncthreads();
        sh[threadIdx.x] += a;
        __syncthreads();
    }
    if (threadIdx.x < nb) bsum[threadIdx.x] = sh[threadIdx.x] - v;  // exclusive
}

__global__ void k_scanC(const int* cnt, const int* bsum, int* off, int* cur) {
    __shared__ int sh[256];
    int i = blockIdx.x * 256 + threadIdx.x;
    int v = (i < NODES) ? cnt[i] : 0;
    sh[threadIdx.x] = v;
    __syncthreads();
    for (int s = 1; s < 256; s <<= 1) {
        int a = ((int)threadIdx.x >= s) ? sh[threadIdx.x - s] : 0;
        __syncthreads();
        sh[threadIdx.x] += a;
        __syncthreads();
    }
    int excl = sh[threadIdx.x] - v + bsum[blockIdx.x];
    if (i < NODES) { off[i] = excl; cur[i] = excl; }
}

__global__ void k_fill(const void* ei, const int* flag, int* cur, int* elist) {
    int tid = blockIdx.x * 256 + threadIdx.x;  // exactly Tn*En
    int is32 = *flag;
    int t = tid / En, e = tid - t * En;
    int src = eget(ei, is32, (size_t)t * 2 * En + e);
    int dst = eget(ei, is32, (size_t)t * 2 * En + En + e);
    int pos = atomicAdd(&cur[t * Nn + dst], 1);
    elist[pos] = t * Nn + src;
}

// h = x @ W_gcn   [Tn*Nn,128] @ [128,64]
__global__ void k_gcn_mm(const float* __restrict__ x, const float* __restrict__ Wg,
                         float* __restrict__ h) {
    __shared__ float wl[FIN * Hh];
    __shared__ float xs[4][FIN];
    int tid = threadIdx.x;
    const float4* Wg4 = (const float4*)Wg;
    float4* wl4 = (float4*)wl;
    for (int i = tid; i < FIN * Hh / 4; i += 256) wl4[i] = Wg4[i];
    int r0 = blockIdx.x * 4;
    const float4* x4 = (const float4*)x + (size_t)r0 * (FIN / 4);
    if (tid < 128) ((float4*)xs)[tid] = x4[tid];
    __syncthreads();
    int c = tid & 63, j = tid >> 6;
    float acc = 0.f;
#pragma unroll 8
    for (int k = 0; k < FIN; k++) acc += xs[j][k] * wl[k * Hh + c];
    h[(size_t)(r0 + j) * Hh + c] = acc;
}

// gout[dst] = ( sum_{src in CSR(dst)} h[src]*dinv[src] + h[dst]*dinv[dst] ) * dinv[dst]
__global__ void k_gather(const int* __restrict__ off, const int* __restrict__ cnt,
                         const int* __restrict__ elist, const float* __restrict__ h,
                         const float* __restrict__ dinv, float* __restrict__ gout) {
    int grp = (blockIdx.x * 256 + threadIdx.x) >> 4;  // 16 threads per node
    int l16 = threadIdx.x & 15;
    int start = off[grp], n = cnt[grp];
    float4 acc = {0.f, 0.f, 0.f, 0.f};
    for (int k = 0; k < n; k++) {
        int s = elist[start + k];
        float ds = dinv[s];
        float4 v = ((const float4*)(h + (size_t)s * Hh))[l16];
        acc.x += v.x * ds;
        acc.y += v.y * ds;
        acc.z += v.z * ds;
        acc.w += v.w * ds;
    }
    float dd = dinv[grp];
    float4 hv = ((const float4*)(h + (size_t)grp * Hh))[l16];
    acc.x = (acc.x + hv.x * dd) * dd;
    acc.y = (acc.y + hv.y * dd) * dd;
    acc.z = (acc.z + hv.z * dd) * dd;
    acc.w = (acc.w + hv.w * dd) * dd;
    ((float4*)(gout + (size_t)grp * Hh))[l16] = acc;
}

// xw = relu(gout + b_gcn) @ W_ih^T + b_ih + b_hh  -> f16 [Tn*Nn][j=0..63][gate=0..3]
__global__ void k_xw(const float* __restrict__ gout, const float* __restrict__ bg,
                     const float* __restrict__ Wih, const float* __restrict__ bih,
                     const float* __restrict__ bhh, _Float16* __restrict__ xw) {
    __shared__ float xs[8 * Hh];
    int tid = threadIdx.x;
    int r0 = blockIdx.x * 8;
    if (tid < 128) {
        float4 v = ((const float4*)(gout + (size_t)r0 * Hh))[tid];
        float4 b = ((const float4*)bg)[tid & 15];
        v.x = fmaxf(v.x + b.x, 0.f);
        v.y = fmaxf(v.y + b.y, 0.f);
        v.z = fmaxf(v.z + b.z, 0.f);
        v.w = fmaxf(v.w + b.w, 0.f);
        ((float4*)xs)[tid] = v;
    }
    __syncthreads();
    int r = tid;  // gate-row 0..255;  col r = q*64 + j  -> store [row][j][q]
    const float4* w4 = (const float4*)(Wih + (size_t)r * Hh);
    float acc[8];
#pragma unroll
    for (int j = 0; j < 8; j++) acc[j] = 0.f;
#pragma unroll
    for (int kk = 0; kk < 16; kk++) {
        float4 w = w4[kk];
#pragma unroll
        for (int j = 0; j < 8; j++) {
            float4 xv = ((const float4*)xs)[j * 16 + kk];
            acc[j] += w.x * xv.x + w.y * xv.y + w.z * xv.z + w.w * xv.w;
        }
    }
    float bias = bih[r] + bhh[r];
    int jj = r & 63, q = r >> 6;
#pragma unroll
    for (int j = 0; j < 8; j++)
        xw[(size_t)(r0 + j) * 256 + jj * 4 + q] = (_Float16)(acc[j] + bias);
}

// One chain per WAVE (64-thread block, no barriers ever). W_hh^T lives in
// 32 B-fragments (128 VGPRs). Lane j owns cell j: gate g = acc[4g+kg][0]
// selected by 3 cndmask. h crosses steps via same-wave LDS (in-order DS pipe).
__global__ void __launch_bounds__(64, 1) k_lstm(const _Float16* __restrict__ xw,
                                                const float* __restrict__ Whh,
                                                float* __restrict__ out) {
    __shared__ __align__(16) _Float16 hlds[64];
    int t = blockIdx.x;
    int lane = threadIdx.x;
    int l = lane & 15;
    int kg = lane >> 4;

    // B frags: frag cg covers gate cols 16cg..16cg+15. B[k][n=l] = Whh[16cg+l][k].
    h8 bf[16][2];
#pragma unroll
    for (int cg = 0; cg < 16; cg++) {
        int row = cg * 16 + l;
#pragma unroll
        for (int half = 0; half < 2; half++) {
            const float* src = Whh + (size_t)row * 64 + kg * 8 + half * 32;
            h8 tmp;
#pragma unroll
            for (int j = 0; j < 8; j++) tmp[j] = (_Float16)src[j];
            bf[cg][half] = tmp;
        }
    }
    hlds[lane] = (_Float16)0.f;

    const h4* xr = (const h4*)(xw + (size_t)t * Nn * 256) + lane;  // row stride 64 h4
    float* ob = out + (size_t)t * Nn * 64;
    h4 cur = xr[0];
    float c = 0.f;
    f4v z = {0.f, 0.f, 0.f, 0.f};

    for (int n = 0; n < Nn; n++) {
        int nn = (n + 1 < Nn) ? n + 1 : n;
        h4 nxt = xr[(size_t)nn * 64];

        h8 a0 = *(const h8*)&hlds[kg * 8];
        h8 a1 = *(const h8*)&hlds[32 + kg * 8];

        f4v acc[16];
#pragma unroll
        for (int cg = 0; cg < 16; cg++) {
            f4v t0 = __builtin_amdgcn_mfma_f32_16x16x32_f16(a0, bf[cg][0], z, 0, 0, 0);
            acc[cg] = __builtin_amdgcn_mfma_f32_16x16x32_f16(a1, bf[cg][1], t0, 0, 0, 0);
        }

        float ge[4];
#pragma unroll
        for (int g = 0; g < 4; g++) {
            float r = acc[4 * g + 0][0];
            r = (kg == 1) ? acc[4 * g + 1][0] : r;
            r = (kg == 2) ? acc[4 * g + 2][0] : r;
            r = (kg == 3) ? acc[4 * g + 3][0] : r;
            ge[g] = r + (float)cur[g];
        }

        float iv = sigm(ge[0]);
        float fv = sigm(ge[1]);
        float gv = tanh_(ge[2]);
        float ov = sigm(ge[3]);
        c = fv * c + iv * gv;
        float hv = ov * tanh_(c);

        ob[(size_t)n * 64 + lane] = hv;
        hlds[lane] = (_Float16)hv;  // same-wave DS: in-order, no barrier needed
        cur = nxt;
    }
}

extern "C" void kernel_launch(void* const* d_in, const int* in_sizes, int n_in,
                              void* d_out, int out_size, void* d_ws, size_t ws_size,
                              hipStream_t stream) {
    const float* x = (const float*)d_in[0];
    const void* ei = d_in[1];
    const float* Wg = (const float*)d_in[2];
    const float* bg = (const float*)d_in[3];
    const float* Wih = (const float*)d_in[4];
    const float* Whh = (const float*)d_in[5];
    const float* bih = (const float*)d_in[6];
    const float* bhh = (const float*)d_in[7];
    float* out = (float*)d_out;

    char* ws = (char*)d_ws;
    _Float16* xw = (_Float16*)(ws);            // 40,960,000
    float* gout = (float*)(ws + 40960000);     // 20,480,000
    float* h = (float*)(ws + 61440000);        // 20,480,000
    float* dinv = (float*)(ws + 81920000);     //    320,000
    int* cnt = (int*)(ws + 82240000);          //    320,000
    int* off = (int*)(ws + 82560000);          //    320,000
    int* cur = (int*)(ws + 82880000);          //    320,000
    int* elist = (int*)(ws + 83200000);        //  5,120,000
    int* bsum = (int*)(ws + 88320000);         //      2,048
    int* flag = (int*)(ws + 88322048);         //         16

    const int NB = (NODES + 255) / 256;  // 313

    hipMemsetAsync(cnt, 0, NODES * sizeof(int), stream);
    k_detect<<<1, 64, 0, stream>>>((const unsigned*)ei, flag);
    k_cnt<<<Tn * En / 256, 256, 0, stream>>>(ei, flag, cnt);
    k_dinv<<<NB, 256, 0, stream>>>(cnt, dinv);
    k_scanA<<<NB, 256, 0, stream>>>(cnt, bsum);
    k_scanB<<<1, 512, 0, stream>>>(bsum, NB);
    k_scanC<<<NB, 256, 0, stream>>>(cnt, bsum, off, cur);
    k_fill<<<Tn * En / 256, 256, 0, stream>>>(ei, flag, cur, elist);
    k_gcn_mm<<<Tn * Nn / 4, 256, 0, stream>>>(x, Wg, h);
    k_gather<<<NODES * 16 / 256, 256, 0, stream>>>(off, cnt, elist, h, dinv, gout);
    k_xw<<<Tn * Nn / 8, 256, 0, stream>>>(gout, bg, Wih, bih, bhh, xw);
    k_lstm<<<Tn, 64, 0, stream>>>(xw, Whh, out);
}

// Round 3
// 3098.012 us; speedup vs baseline: 1.6304x; 1.6236x over previous
//
#include <hip/hip_runtime.h>

#define Tn 8
#define Nn 10000
#define FIN 128
#define Hh 64
#define En 160000
#define NODES (Tn * Nn)

typedef _Float16 h8 __attribute__((ext_vector_type(8)));
typedef _Float16 h4 __attribute__((ext_vector_type(4)));
typedef float f4v __attribute__((ext_vector_type(4)));

__device__ __forceinline__ float sigm(float x) {
    float e = __builtin_amdgcn_exp2f(-1.4426950408889634f * x);
    return __builtin_amdgcn_rcpf(1.0f + e);
}
__device__ __forceinline__ float tanh_(float x) {
    float e = __builtin_amdgcn_exp2f(2.8853900817779268f * x);
    return 1.0f - 2.0f * __builtin_amdgcn_rcpf(1.0f + e);
}

// edge_index may arrive as int32 or int64; detect by checking high words.
__global__ void k_detect(const unsigned* ei, int* flag) {
    unsigned a = 0;
    for (int i = threadIdx.x; i < 4096; i += 64) a |= ei[2 * i + 1];
    unsigned long long b = __ballot(a != 0);
    if (threadIdx.x == 0) flag[0] = (b != 0ull) ? 1 : 0;  // 1 => int32
}

__device__ __forceinline__ int eget(const void* ei, int is32, size_t pos) {
    return is32 ? ((const int*)ei)[pos] : (int)((const long long*)ei)[pos];
}

__global__ void k_cnt(const void* ei, const int* flag, int* cnt) {
    int tid = blockIdx.x * 256 + threadIdx.x;  // exactly Tn*En
    int is32 = *flag;
    int t = tid / En, e = tid - t * En;
    int dst = eget(ei, is32, (size_t)t * 2 * En + En + e);
    atomicAdd(&cnt[t * Nn + dst], 1);
}

__global__ void k_dinv(const int* cnt, float* dinv) {
    int i = blockIdx.x * 256 + threadIdx.x;
    if (i < NODES) dinv[i] = rsqrtf((float)cnt[i] + 1.0f);  // +1 self-loop
}

// --- exclusive prefix sum over cnt[NODES]: A) block sums, B) scan sums, C) combine
__global__ void k_scanA(const int* cnt, int* bsum) {
    __shared__ int sh[256];
    int i = blockIdx.x * 256 + threadIdx.x;
    sh[threadIdx.x] = (i < NODES) ? cnt[i] : 0;
    __syncthreads();
    for (int s = 128; s > 0; s >>= 1) {
        if (threadIdx.x < s) sh[threadIdx.x] += sh[threadIdx.x + s];
        __syncthreads();
    }
    if (threadIdx.x == 0) bsum[blockIdx.x] = sh[0];
}

__global__ void k_scanB(int* bsum, int nb) {
    __shared__ int sh[512];
    int v = (threadIdx.x < nb) ? bsum[threadIdx.x] : 0;
    sh[threadIdx.x] = v;
    __syncthreads();
    for (int s = 1; s < 512; s <<= 1) {
        int a = ((int)threadIdx.x >= s) ? sh[threadIdx.x - s] : 0;
        __syncthreads();
        sh[threadIdx.x] += a;
        __syncthreads();
    }
    if (threadIdx.x < nb) bsum[threadIdx.x] = sh[threadIdx.x] - v;  // exclusive
}

__global__ void k_scanC(const int* cnt, const int* bsum, int* off, int* cur) {
    __shared__ int sh[256];
    int i = blockIdx.x * 256 + threadIdx.x;
    int v = (i < NODES) ? cnt[i] : 0;
    sh[threadIdx.x] = v;
    __syncthreads();
    for (int s = 1; s < 256; s <<= 1) {
        int a = ((int)threadIdx.x >= s) ? sh[threadIdx.x - s] : 0;
        __syncthreads();
        sh[threadIdx.x] += a;
        __syncthreads();
    }
    int excl = sh[threadIdx.x] - v + bsum[blockIdx.x];
    if (i < NODES) { off[i] = excl; cur[i] = excl; }
}

__global__ void k_fill(const void* ei, const int* flag, int* cur, int* elist) {
    int tid = blockIdx.x * 256 + threadIdx.x;  // exactly Tn*En
    int is32 = *flag;
    int t = tid / En, e = tid - t * En;
    int src = eget(ei, is32, (size_t)t * 2 * En + e);
    int dst = eget(ei, is32, (size_t)t * 2 * En + En + e);
    int pos = atomicAdd(&cur[t * Nn + dst], 1);
    elist[pos] = t * Nn + src;
}

// h = x @ W_gcn   [Tn*Nn,128] @ [128,64]
__global__ void k_gcn_mm(const float* __restrict__ x, const float* __restrict__ Wg,
                         float* __restrict__ h) {
    __shared__ float wl[FIN * Hh];
    __shared__ float xs[4][FIN];
    int tid = threadIdx.x;
    const float4* Wg4 = (const float4*)Wg;
    float4* wl4 = (float4*)wl;
    for (int i = tid; i < FIN * Hh / 4; i += 256) wl4[i] = Wg4[i];
    int r0 = blockIdx.x * 4;
    const float4* x4 = (const float4*)x + (size_t)r0 * (FIN / 4);
    if (tid < 128) ((float4*)xs)[tid] = x4[tid];
    __syncthreads();
    int c = tid & 63, j = tid >> 6;
    float acc = 0.f;
#pragma unroll 8
    for (int k = 0; k < FIN; k++) acc += xs[j][k] * wl[k * Hh + c];
    h[(size_t)(r0 + j) * Hh + c] = acc;
}

// gout[dst] = ( sum_{src in CSR(dst)} h[src]*dinv[src] + h[dst]*dinv[dst] ) * dinv[dst]
__global__ void k_gather(const int* __restrict__ off, const int* __restrict__ cnt,
                         const int* __restrict__ elist, const float* __restrict__ h,
                         const float* __restrict__ dinv, float* __restrict__ gout) {
    int grp = (blockIdx.x * 256 + threadIdx.x) >> 4;  // 16 threads per node
    int l16 = threadIdx.x & 15;
    int start = off[grp], n = cnt[grp];
    float4 acc = {0.f, 0.f, 0.f, 0.f};
    for (int k = 0; k < n; k++) {
        int s = elist[start + k];
        float ds = dinv[s];
        float4 v = ((const float4*)(h + (size_t)s * Hh))[l16];
        acc.x += v.x * ds;
        acc.y += v.y * ds;
        acc.z += v.z * ds;
        acc.w += v.w * ds;
    }
    float dd = dinv[grp];
    float4 hv = ((const float4*)(h + (size_t)grp * Hh))[l16];
    acc.x = (acc.x + hv.x * dd) * dd;
    acc.y = (acc.y + hv.y * dd) * dd;
    acc.z = (acc.z + hv.z * dd) * dd;
    acc.w = (acc.w + hv.w * dd) * dd;
    ((float4*)(gout + (size_t)grp * Hh))[l16] = acc;
}

// xw = relu(gout + b_gcn) @ W_ih^T + b_ih + b_hh  -> f16 [Tn*Nn][j=0..63][gate=0..3]
__global__ void k_xw(const float* __restrict__ gout, const float* __restrict__ bg,
                     const float* __restrict__ Wih, const float* __restrict__ bih,
                     const float* __restrict__ bhh, _Float16* __restrict__ xw) {
    __shared__ float xs[8 * Hh];
    int tid = threadIdx.x;
    int r0 = blockIdx.x * 8;
    if (tid < 128) {
        float4 v = ((const float4*)(gout + (size_t)r0 * Hh))[tid];
        float4 b = ((const float4*)bg)[tid & 15];
        v.x = fmaxf(v.x + b.x, 0.f);
        v.y = fmaxf(v.y + b.y, 0.f);
        v.z = fmaxf(v.z + b.z, 0.f);
        v.w = fmaxf(v.w + b.w, 0.f);
        ((float4*)xs)[tid] = v;
    }
    __syncthreads();
    int r = tid;  // gate-row 0..255;  col r = q*64 + j  -> store [row][j][q]
    const float4* w4 = (const float4*)(Wih + (size_t)r * Hh);
    float acc[8];
#pragma unroll
    for (int j = 0; j < 8; j++) acc[j] = 0.f;
#pragma unroll
    for (int kk = 0; kk < 16; kk++) {
        float4 w = w4[kk];
#pragma unroll
        for (int j = 0; j < 8; j++) {
            float4 xv = ((const float4*)xs)[j * 16 + kk];
            acc[j] += w.x * xv.x + w.y * xv.y + w.z * xv.z + w.w * xv.w;
        }
    }
    float bias = bih[r] + bhh[r];
    int jj = r & 63, q = r >> 6;
#pragma unroll
    for (int j = 0; j < 8; j++)
        xw[(size_t)(r0 + j) * 256 + jj * 4 + q] = (_Float16)(acc[j] + bias);
}

// One chain per 4-wave block (R1 layout): wave w owns gate-cols 16w..16w+15 of all
// 4 gate quadrants -> 8 MFMAs/wave/step (min per-SIMD issue). Cross-wave h exchange
// via LDS double buffer + RAW s_barrier that drains ONLY lgkmcnt: global xw
// prefetch (4 steps deep) and out stores stay in flight across the barrier.
__global__ void __launch_bounds__(256, 1) k_lstm(const _Float16* __restrict__ xw,
                                                 const float* __restrict__ Whh,
                                                 float* __restrict__ out) {
    __shared__ __align__(16) _Float16 hb[2][64];
    int t = blockIdx.x;
    int tid = threadIdx.x;
    int w = tid >> 6;
    int lane = tid & 63;
    int l = lane & 15;
    int kg = lane >> 4;
    int col = w * 16 + l;  // cell index this lane computes

    // B frags: quadrant q covers W_hh rows q*64+16w .. q*64+16w+15.
    h8 bf[4][2];
#pragma unroll
    for (int q = 0; q < 4; q++) {
        int row = q * 64 + col;
#pragma unroll
        for (int half = 0; half < 2; half++) {
            const float* src = Whh + (size_t)row * 64 + half * 32 + kg * 8;
            h8 tmp;
#pragma unroll
            for (int j = 0; j < 8; j++) tmp[j] = (_Float16)src[j];
            bf[q][half] = tmp;
        }
    }
    if (tid < 128) hb[tid >> 6][tid & 63] = (_Float16)0.f;
    __syncthreads();  // one full barrier for init only

    const h4* xr = (const h4*)(xw + (size_t)t * Nn * 256) + col;  // stride 64 h4/row
    float* ob = out + (size_t)t * Nn * 64;

    h4 pf[4];
#pragma unroll
    for (int d = 0; d < 4; d++) pf[d] = xr[(size_t)d * 64];
    float c = 0.f;

    for (int n4 = 0; n4 < Nn; n4 += 4) {
#pragma unroll
        for (int u = 0; u < 4; u++) {
            int n = n4 + u;
            h4 xc = pf[u];
            int np = n + 4;
            if (np >= Nn) np = Nn - 1;
            pf[u] = xr[(size_t)np * 64];

            h8 a0 = *(const h8*)&hb[n & 1][kg * 8];
            h8 a1 = *(const h8*)&hb[n & 1][32 + kg * 8];

            f4v acc0 = {(float)xc[0], 0.f, 0.f, 0.f};
            f4v acc1 = {(float)xc[1], 0.f, 0.f, 0.f};
            f4v acc2 = {(float)xc[2], 0.f, 0.f, 0.f};
            f4v acc3 = {(float)xc[3], 0.f, 0.f, 0.f};
            acc0 = __builtin_amdgcn_mfma_f32_16x16x32_f16(a0, bf[0][0], acc0, 0, 0, 0);
            acc0 = __builtin_amdgcn_mfma_f32_16x16x32_f16(a1, bf[0][1], acc0, 0, 0, 0);
            acc1 = __builtin_amdgcn_mfma_f32_16x16x32_f16(a0, bf[1][0], acc1, 0, 0, 0);
            acc1 = __builtin_amdgcn_mfma_f32_16x16x32_f16(a1, bf[1][1], acc1, 0, 0, 0);
            acc2 = __builtin_amdgcn_mfma_f32_16x16x32_f16(a0, bf[2][0], acc2, 0, 0, 0);
            acc2 = __builtin_amdgcn_mfma_f32_16x16x32_f16(a1, bf[2][1], acc2, 0, 0, 0);
            acc3 = __builtin_amdgcn_mfma_f32_16x16x32_f16(a0, bf[3][0], acc3, 0, 0, 0);
            acc3 = __builtin_amdgcn_mfma_f32_16x16x32_f16(a1, bf[3][1], acc3, 0, 0, 0);

            float iv = sigm(acc0[0]);
            float fv = sigm(acc1[0]);
            float gv = tanh_(acc2[0]);
            float ov = sigm(acc3[0]);
            c = fv * c + iv * gv;
            float hv = ov * tanh_(c);

            if (lane < 16) {  // kg==0 lanes: 16 distinct cols per wave
                ob[(size_t)n * 64 + col] = hv;
                hb[(n + 1) & 1][col] = (_Float16)hv;
            }
            // RAW barrier: drain LDS ops only; global loads/stores stay in flight.
            asm volatile("s_waitcnt lgkmcnt(0)\n\ts_barrier" ::: "memory");
        }
    }
}

extern "C" void kernel_launch(void* const* d_in, const int* in_sizes, int n_in,
                              void* d_out, int out_size, void* d_ws, size_t ws_size,
                              hipStream_t stream) {
    const float* x = (const float*)d_in[0];
    const void* ei = d_in[1];
    const float* Wg = (const float*)d_in[2];
    const float* bg = (const float*)d_in[3];
    const float* Wih = (const float*)d_in[4];
    const float* Whh = (const float*)d_in[5];
    const float* bih = (const float*)d_in[6];
    const float* bhh = (const float*)d_in[7];
    float* out = (float*)d_out;

    char* ws = (char*)d_ws;
    _Float16* xw = (_Float16*)(ws);            // 40,960,000
    float* gout = (float*)(ws + 40960000);     // 20,480,000
    float* h = (float*)(ws + 61440000);        // 20,480,000
    float* dinv = (float*)(ws + 81920000);     //    320,000
    int* cnt = (int*)(ws + 82240000);          //    320,000
    int* off = (int*)(ws + 82560000);          //    320,000
    int* cur = (int*)(ws + 82880000);          //    320,000
    int* elist = (int*)(ws + 83200000);        //  5,120,000
    int* bsum = (int*)(ws + 88320000);         //      2,048
    int* flag = (int*)(ws + 88322048);         //         16

    const int NB = (NODES + 255) / 256;  // 313

    hipMemsetAsync(cnt, 0, NODES * sizeof(int), stream);
    k_detect<<<1, 64, 0, stream>>>((const unsigned*)ei, flag);
    k_cnt<<<Tn * En / 256, 256, 0, stream>>>(ei, flag, cnt);
    k_dinv<<<NB, 256, 0, stream>>>(cnt, dinv);
    k_scanA<<<NB, 256, 0, stream>>>(cnt, bsum);
    k_scanB<<<1, 512, 0, stream>>>(bsum, NB);
    k_scanC<<<NB, 256, 0, stream>>>(cnt, bsum, off, cur);
    k_fill<<<Tn * En / 256, 256, 0, stream>>>(ei, flag, cur, elist);
    k_gcn_mm<<<Tn * Nn / 4, 256, 0, stream>>>(x, Wg, h);
    k_gather<<<NODES * 16 / 256, 256, 0, stream>>>(off, cnt, elist, h, dinv, gout);
    k_xw<<<Tn * Nn / 8, 256, 0, stream>>>(gout, bg, Wih, bih, bhh, xw);
    k_lstm<<<Tn, 256, 0, stream>>>(xw, Whh, out);
}